// Round 10
// baseline (252.376 us; speedup 1.0000x reference)
//
#include <hip/hip_runtime.h>

#define D 128
#define BROWS 512       // rows per coarse bucket
#define LOGB 9
#define NBMAX 256       // max buckets (N <= 131072)
#define CAP 9216        // entries per bucket region (mean 8192, +11 sigma)
#define CHUNK 4096      // edges per k_bin chunk
#define LDSW 136        // padded LDS stride for W planes

typedef __attribute__((ext_vector_type(8))) short bf16x8;
typedef __attribute__((ext_vector_type(4))) float f32x4;

__device__ inline unsigned short f2bf(float f) {
    unsigned u = __float_as_uint(f);
    u += 0x7FFFu + ((u >> 16) & 1u);
    return (unsigned short)(u >> 16);
}
__device__ inline float bf2f(unsigned short h) {
    return __uint_as_float((unsigned)h << 16);
}
__device__ inline float bflo(unsigned u) { return __uint_as_float(u << 16); }
__device__ inline float bfhi(unsigned u) { return __uint_as_float(u & 0xFFFF0000u); }

// Bin edges into NB coarse buckets; packed entry = (local_row<<17)|col.
// Blocks 0-7 additionally pre-convert W to bf16 hi/lo (once for the pipeline).
__global__ __launch_bounds__(512) void k_bin(const int* __restrict__ row,
                                             const int* __restrict__ col,
                                             int E, int* __restrict__ gcur,
                                             unsigned* __restrict__ ebuf,
                                             const float* __restrict__ W,
                                             unsigned short* __restrict__ Wbh,
                                             unsigned short* __restrict__ Wbl) {
    __shared__ int lhist[NBMAX];
    __shared__ int sc[NBMAX];
    __shared__ int gbase[NBMAX];
    __shared__ unsigned sstage[CHUNK];
    __shared__ int sdest[CHUNK];
    int t = threadIdx.x;
    if (blockIdx.x < 8) {   // W -> bf16 hi/lo, 2048 elements per block
        int base = blockIdx.x * 2048 + t;
        #pragma unroll
        for (int i = 0; i < 4; ++i) {
            int idx = base + i * 512;
            float wv = W[idx];
            unsigned short h = f2bf(wv);
            Wbh[idx] = h;
            Wbl[idx] = f2bf(wv - bf2f(h));
        }
    }
    int base = blockIdx.x * CHUNK;
    if (t < NBMAX) lhist[t] = 0;
    __syncthreads();
    int b[8], p[8]; unsigned pk[8];
    #pragma unroll
    for (int i = 0; i < 8; ++i) {
        int idx = base + i * 512 + t;
        if (idx < E) {
            int r = row[idx], c = col[idx];
            b[i] = r >> LOGB;
            pk[i] = ((unsigned)(r & (BROWS - 1)) << 17) | (unsigned)c;
            p[i] = atomicAdd(&lhist[b[i]], 1);
        } else b[i] = -1;
    }
    __syncthreads();
    if (t < 64) {   // wave-0 scan, 4 bins per lane (256 bins)
        int a0 = lhist[4*t], a1 = lhist[4*t+1], a2 = lhist[4*t+2], a3 = lhist[4*t+3];
        int s = a0 + a1 + a2 + a3;
        int incl = s;
        #pragma unroll
        for (int m = 1; m < 64; m <<= 1) {
            int tmp = __shfl_up(incl, m);
            if (t >= m) incl += tmp;
        }
        int excl = incl - s;
        sc[4*t] = excl; sc[4*t+1] = excl + a0;
        sc[4*t+2] = excl + a0 + a1; sc[4*t+3] = excl + a0 + a1 + a2;
        if (a0 > 0) gbase[4*t]   = atomicAdd(&gcur[4*t],   a0);
        if (a1 > 0) gbase[4*t+1] = atomicAdd(&gcur[4*t+1], a1);
        if (a2 > 0) gbase[4*t+2] = atomicAdd(&gcur[4*t+2], a2);
        if (a3 > 0) gbase[4*t+3] = atomicAdd(&gcur[4*t+3], a3);
    }
    __syncthreads();
    #pragma unroll
    for (int i = 0; i < 8; ++i) {
        if (b[i] >= 0) {
            int lidx = sc[b[i]] + p[i];
            int rel = gbase[b[i]] + p[i];
            sstage[lidx] = pk[i];
            sdest[lidx] = (rel < CAP) ? (b[i] * CAP + rel) : -1;
        }
    }
    __syncthreads();
    int total = sc[NBMAX - 1] + lhist[NBMAX - 1];
    for (int i = t; i < total; i += 512) {
        int d = sdest[i];
        if (d >= 0) ebuf[d] = sstage[i];
    }
}

// One block per bucket: stage bucket in LDS, degree hist + scan -> dvals/rptr,
// counting-sort csr_col.
__global__ __launch_bounds__(1024) void k_group(const int* __restrict__ gcur,
                                                const unsigned* __restrict__ ebuf,
                                                int N, int NBK,
                                                float* __restrict__ dvals,
                                                int* __restrict__ rptr,
                                                int* __restrict__ csr_col,
                                                unsigned short* __restrict__ Hs) {
    __shared__ unsigned sebuf[CAP];   // 36 KB
    __shared__ int lhist[BROWS];      // hist, then cursor
    __shared__ int wtot[8];
    __shared__ int woff[8];
    __shared__ int sebase;
    int bkt = blockIdx.x, t = threadIdx.x;
    int cnt = gcur[bkt]; if (cnt > CAP) cnt = CAP;
    if (t < 64) {
        int acc = 0;
        for (int i = t; i < bkt; i += 64) {
            int g = gcur[i];
            acc += (g > CAP) ? CAP : g;
        }
        #pragma unroll
        for (int m = 1; m < 64; m <<= 1) acc += __shfl_xor(acc, m);
        if (t == 0) sebase = acc;
    }
    if (t < BROWS) lhist[t] = 0;
    __syncthreads();
    const unsigned* ep = ebuf + (size_t)bkt * CAP;
    for (int i = t; i < cnt; i += 1024) {
        unsigned e = ep[i];
        sebuf[i] = e;
        atomicAdd(&lhist[e >> 17], 1);
    }
    __syncthreads();
    int lane = t & 63, wv = t >> 6;
    int v = 0, incl = 0;
    if (t < BROWS) {    // 8 waves scan 512 degrees
        v = lhist[t];
        incl = v;
        #pragma unroll
        for (int m = 1; m < 64; m <<= 1) {
            int tmp = __shfl_up(incl, m);
            if (lane >= m) incl += tmp;
        }
        if (lane == 63) wtot[wv] = incl;
    }
    __syncthreads();
    if (t < 8) {
        int w = wtot[t];
        int wincl = w;
        #pragma unroll
        for (int m = 1; m < 8; m <<= 1) {
            int tmp = __shfl_up(wincl, m);
            if (t >= m) wincl += tmp;
        }
        woff[t] = wincl - w;
    }
    __syncthreads();
    int ebase = sebase;
    if (t < BROWS) {
        int excl = woff[wv] + incl - v;
        int r = (bkt << LOGB) + t;
        if (r < N) {
            rptr[r] = ebase + excl;
            dvals[r] = rsqrtf((float)v);
        }
        lhist[t] = excl;              // becomes running cursor
    }
    if (bkt == NBK - 1 && t == 0) rptr[N] = ebase + cnt;
    if (bkt == 0 && t == 0) dvals[N] = 0.f;   // pad slot
    if (bkt == 0 && t < 64)                    // zero row N of Hs (gather pad)
        ((unsigned*)(Hs + (size_t)N * D))[t] = 0u;
    __syncthreads();
    for (int i = t; i < cnt; i += 1024) {
        unsigned e = sebuf[i];
        int rr = (int)(e >> 17);
        int p = atomicAdd(&lhist[rr], 1);
        csr_col[ebase + p] = (int)(e & 0x1FFFFu);
    }
}

// GEMM-FIRST: Hs[r][:] = bf16(d_r * (x[r] @ W^T + b)).
__global__ __launch_bounds__(256, 2) void k_gc(const float* __restrict__ x,
                                               const unsigned short* __restrict__ Wbh,
                                               const unsigned short* __restrict__ Wbl,
                                               const float* __restrict__ b,
                                               const float* __restrict__ dvals,
                                               unsigned short* __restrict__ Hs, int N) {
    __shared__ unsigned short Whi[128 * LDSW];   // 34.8 KB (reused as stage)
    __shared__ unsigned short Wlo[128 * LDSW];
    __shared__ float bs[D];
    int t = threadIdx.x;
    #pragma unroll
    for (int i = 0; i < 16; ++i) {
        int idx4 = i * 256 + t;          // ushort4 index, 4096 total
        int r = idx4 >> 5;
        int c = (idx4 & 31) * 4;
        ((ushort4*)&Whi[r * LDSW + c])[0] = ((const ushort4*)Wbh)[idx4];
        ((ushort4*)&Wlo[r * LDSW + c])[0] = ((const ushort4*)Wbl)[idx4];
    }
    if (t < D) bs[t] = b[t];
    __syncthreads();

    int wave = t >> 6, lane = t & 63;
    int quad = lane >> 4, mrow = lane & 15;
    int row_base = blockIdx.x * 128 + wave * 32;

    bf16x8 Ahi[2][4], Alo[2][4];
    #pragma unroll
    for (int s = 0; s < 2; ++s) {
        int grow = row_base + s * 16 + mrow;
        bool ok = grow < N;
        const float* xrow = x + (size_t)(ok ? grow : 0) * D;
        #pragma unroll
        for (int kk = 0; kk < 4; ++kk) {
            int k0 = kk * 32 + quad * 8;
            float4 f0 = ok ? ((const float4*)(xrow + k0))[0] : make_float4(0, 0, 0, 0);
            float4 f1 = ok ? ((const float4*)(xrow + k0))[1] : make_float4(0, 0, 0, 0);
            float fv[8] = {f0.x, f0.y, f0.z, f0.w, f1.x, f1.y, f1.z, f1.w};
            #pragma unroll
            for (int j = 0; j < 8; ++j) {
                unsigned short h = f2bf(fv[j]);
                Ahi[s][kk][j] = (short)h;
                Alo[s][kk][j] = (short)f2bf(fv[j] - bf2f(h));
            }
        }
    }

    f32x4 acc[2][8];
    #pragma unroll
    for (int s = 0; s < 2; ++s)
        #pragma unroll
        for (int ct = 0; ct < 8; ++ct)
            acc[s][ct] = (f32x4){0.f, 0.f, 0.f, 0.f};

    #pragma unroll
    for (int ct = 0; ct < 8; ++ct) {
        int wrow = ct * 16 + mrow;
        #pragma unroll
        for (int kk = 0; kk < 4; ++kk) {
            int off = wrow * LDSW + kk * 32 + quad * 8;
            bf16x8 Bhi = *(const bf16x8*)&Whi[off];
            bf16x8 Blo = *(const bf16x8*)&Wlo[off];
            #pragma unroll
            for (int s = 0; s < 2; ++s) {
                acc[s][ct] = __builtin_amdgcn_mfma_f32_16x16x32_bf16(Ahi[s][kk], Bhi, acc[s][ct], 0, 0, 0);
                acc[s][ct] = __builtin_amdgcn_mfma_f32_16x16x32_bf16(Alo[s][kk], Bhi, acc[s][ct], 0, 0, 0);
                acc[s][ct] = __builtin_amdgcn_mfma_f32_16x16x32_bf16(Ahi[s][kk], Blo, acc[s][ct], 0, 0, 0);
            }
        }
    }

    __syncthreads();                 // all waves done reading Whi/Wlo
    unsigned short* stage = Whi;     // alias: 128 x LDSW bf16 output tile
    #pragma unroll
    for (int s = 0; s < 2; ++s) {
        #pragma unroll
        for (int r = 0; r < 4; ++r) {
            int grow = row_base + s * 16 + quad * 4 + r;
            float dv = dvals[(grow < N) ? grow : N];   // dvals[N]=0
            int lrow = wave * 32 + s * 16 + quad * 4 + r;
            #pragma unroll
            for (int ct = 0; ct < 8; ++ct) {
                int col = ct * 16 + mrow;
                stage[lrow * LDSW + col] = f2bf(dv * (acc[s][ct][r] + bs[col]));
            }
        }
    }
    __syncthreads();
    for (int i = t; i < 128 * 16; i += 256) {   // 16B granules: 128 rows x 16
        int lrow = i >> 4;
        int g = i & 15;
        int grow = blockIdx.x * 128 + lrow;
        if (grow < N)
            ((uint4*)Hs)[(size_t)grow * 16 + g] =
                ((const uint4*)&stage[lrow * LDSW])[g];
    }
}

#define ACC8(v) do { \
    a[0] += bflo((v).x); a[1] += bfhi((v).x); \
    a[2] += bflo((v).y); a[3] += bfhi((v).y); \
    a[4] += bflo((v).z); a[5] += bfhi((v).z); \
    a[6] += bflo((v).w); a[7] += bfhi((v).w); } while (0)

// Wave per row over Hs, final-output kernel. HAND-SOFTWARE-PIPELINED 2-deep:
// prologue loads chunk 0; each iteration loads chunk j+1 into fresh regs
// (q0..q3) THEN accumulates chunk j (p0..p3); rotate. The next-chunk values
// are live ACROSS the ACC block by dataflow, so no register allocator can
// serialize this into the VGPR=24/32 one-load-at-a-time variants (R2/R8) —
// the liveness is structural. This is the transformation R1's compiler did
// by luck (VGPR 42, 77 us); now it's deterministic. No sched pragmas
// (R5-R7: every pinning attempt regressed).
__global__ __launch_bounds__(256) void k_rows(const unsigned short* __restrict__ Hs,
                                              const int* __restrict__ rptr,
                                              const int* __restrict__ csr_col,
                                              const float* __restrict__ dvals,
                                              float* __restrict__ out, int N) {
    int wid = (blockIdx.x * blockDim.x + threadIdx.x) >> 6;
    if (wid >= N) return;
    int lane = threadIdx.x & 63;
    int grp = lane >> 4, sl = lane & 15;
    int s = rptr[wid];
    int n = rptr[wid + 1] - s;
    const uint4* hv = (const uint4*)Hs;   // 16B granules, 16 per row

    int cc = csr_col[s + lane];           // unconditional (csr_col padded +64)
    int ccreg = (lane < n) ? cc : N;      // pad lanes -> zero row
    uint4 vself = hv[(size_t)wid * 16 + sl];

    float a[8] = {0.f, 0.f, 0.f, 0.f, 0.f, 0.f, 0.f, 0.f};
    int nf = (n < 64) ? n : 64;           // n >= 1 always (self edge in rows)

    // prologue: chunk 0 (pad lanes read the zero row -> contribute 0.0)
    int c0 = __shfl(ccreg, grp);
    int c1 = __shfl(ccreg, grp + 4);
    int c2 = __shfl(ccreg, grp + 8);
    int c3 = __shfl(ccreg, grp + 12);
    uint4 p0 = hv[(size_t)c0 * 16 + sl];
    uint4 p1 = hv[(size_t)c1 * 16 + sl];
    uint4 p2 = hv[(size_t)c2 * 16 + sl];
    uint4 p3 = hv[(size_t)c3 * 16 + sl];

    for (int k0 = 16; k0 < nf; k0 += 16) {
        int i0 = k0 + grp;                // shuffle idx < 64 always
        int d0 = __shfl(ccreg, i0);
        int d1 = __shfl(ccreg, i0 + 4);
        int d2 = __shfl(ccreg, i0 + 8);
        int d3 = __shfl(ccreg, i0 + 12);
        uint4 q0 = hv[(size_t)d0 * 16 + sl];   // next chunk in flight...
        uint4 q1 = hv[(size_t)d1 * 16 + sl];
        uint4 q2 = hv[(size_t)d2 * 16 + sl];
        uint4 q3 = hv[(size_t)d3 * 16 + sl];
        ACC8(p0); ACC8(p1); ACC8(p2); ACC8(p3); // ...while current chunk ACCs
        p0 = q0; p1 = q1; p2 = q2; p3 = q3;
    }
    ACC8(p0); ACC8(p1); ACC8(p2); ACC8(p3);     // epilogue: last chunk

    if (__builtin_expect(n > 64, 0)) {    // pathological high-degree fallback
        for (int idx = 64 + grp; idx < n; idx += 4) {
            int c = csr_col[s + idx];
            uint4 v = hv[(size_t)c * 16 + sl];
            ACC8(v);
        }
    }
    if (grp == 0) ACC8(vself);            // self-loop term

    #pragma unroll
    for (int j = 0; j < 8; ++j) {
        a[j] += __shfl_xor(a[j], 16);
        a[j] += __shfl_xor(a[j], 32);
    }
    float dr = dvals[wid];
    if (grp < 2) {
        float4 o = (grp == 0) ? make_float4(a[0], a[1], a[2], a[3])
                              : make_float4(a[4], a[5], a[6], a[7]);
        o.x *= dr; o.y *= dr; o.z *= dr; o.w *= dr;
        ((float4*)(out + (size_t)wid * D))[sl * 2 + grp] = o;
    }
}

extern "C" void kernel_launch(void* const* d_in, const int* in_sizes, int n_in,
                              void* d_out, int out_size, void* d_ws, size_t ws_size,
                              hipStream_t stream) {
    const float* x  = (const float*)d_in[0];
    const int*   ei = (const int*)d_in[1];
    const float* W  = (const float*)d_in[2];
    const float* b  = (const float*)d_in[3];
    float* out = (float*)d_out;
    int N = in_sizes[0] / D;
    int E = in_sizes[1] / 2;
    int NB = (N + BROWS - 1) / BROWS;        // 196
    int NCH = (E + CHUNK - 1) / CHUNK;       // 391

    int*            gcur    = (int*)d_ws;                // NBMAX
    int*            rptr    = gcur + NBMAX;              // N+1
    float*          dvals   = (float*)(rptr + N + 1);    // N+1 (dvals[N]=0 pad)
    int*            csr_col = (int*)(dvals + N + 1);     // E+64 (uncond read pad)
    unsigned*       ebuf    = (unsigned*)(csr_col + E + 64);  // NB*CAP
    unsigned short* Wbh     = (unsigned short*)(ebuf + (size_t)NB * CAP);  // 16384
    unsigned short* Wbl     = Wbh + D * D;                                  // 16384
    uintptr_t hs_addr = (uintptr_t)(Wbl + D * D);
    hs_addr = (hs_addr + 15) & ~(uintptr_t)15;
    unsigned short* Hs = (unsigned short*)hs_addr;  // (N+1)*D bf16; row N zeros

    hipMemsetAsync(gcur, 0, NBMAX * sizeof(int), stream);
    k_bin<<<NCH, 512, 0, stream>>>(ei, ei + E, E, gcur, ebuf, W, Wbh, Wbl);
    k_group<<<NB, 1024, 0, stream>>>(gcur, ebuf, N, NB, dvals, rptr, csr_col, Hs);
    k_gc<<<(N + 127) / 128, 256, 0, stream>>>(x, Wbh, Wbl, b, dvals, Hs, N);
    k_rows<<<(N + 3) / 4, 256, 0, stream>>>(Hs, rptr, csr_col, dvals, out, N);
}

// Round 11
// 236.774 us; speedup vs baseline: 1.0659x; 1.0659x over previous
//
#include <hip/hip_runtime.h>

#define D 128
#define BROWS 512       // rows per coarse bucket
#define LOGB 9
#define NBMAX 256       // max bins (N <= 131072)
#define CHUNK 4096      // edges per k_bin chunk
#define SCAP 10240      // LDS staging capacity per bucket (mean 8192, +22 sigma)
#define NCHMAX 512      // max chunks (E <= 2M)
#define LDSW 136        // padded LDS stride for W planes

typedef __attribute__((ext_vector_type(8))) short bf16x8;
typedef __attribute__((ext_vector_type(4))) float f32x4;

__device__ inline unsigned short f2bf(float f) {
    unsigned u = __float_as_uint(f);
    u += 0x7FFFu + ((u >> 16) & 1u);
    return (unsigned short)(u >> 16);
}
__device__ inline float bf2f(unsigned short h) {
    return __uint_as_float((unsigned)h << 16);
}
__device__ inline float bflo(unsigned u) { return __uint_as_float(u << 16); }
__device__ inline float bfhi(unsigned u) { return __uint_as_float(u & 0xFFFF0000u); }

// Bin edges into 256 bins; packed entry = (local_row<<17)|col. Entries are
// bin-SORTED within the chunk but stored CONTIGUOUSLY at ebuf[chunk*CHUNK]
// (full-line coalesced flush — kills R1's 7x write-allocate amplification).
// Per-chunk bin prefix table sc_g[chunk][0..256] (1 KB, coalesced) lets
// k_group find each bin's segment. No global atomics, no gcur, no CAP.
// Blocks 0-7 additionally pre-convert W to bf16 hi/lo.
__global__ __launch_bounds__(512) void k_bin(const int* __restrict__ row,
                                             const int* __restrict__ col,
                                             int E, unsigned* __restrict__ ebuf,
                                             int* __restrict__ sc_g,
                                             const float* __restrict__ W,
                                             unsigned short* __restrict__ Wbh,
                                             unsigned short* __restrict__ Wbl) {
    __shared__ int lhist[NBMAX];
    __shared__ int sc[NBMAX];
    __shared__ unsigned sstage[CHUNK];
    int t = threadIdx.x;
    if (blockIdx.x < 8) {   // W -> bf16 hi/lo, 2048 elements per block
        int wb = blockIdx.x * 2048 + t;
        #pragma unroll
        for (int i = 0; i < 4; ++i) {
            int idx = wb + i * 512;
            float wv = W[idx];
            unsigned short h = f2bf(wv);
            Wbh[idx] = h;
            Wbl[idx] = f2bf(wv - bf2f(h));
        }
    }
    int base = blockIdx.x * CHUNK;
    if (t < NBMAX) lhist[t] = 0;
    __syncthreads();
    int b[8], p[8]; unsigned pk[8];
    #pragma unroll
    for (int i = 0; i < 8; ++i) {
        int idx = base + i * 512 + t;
        if (idx < E) {
            int r = row[idx], c = col[idx];
            b[i] = r >> LOGB;
            pk[i] = ((unsigned)(r & (BROWS - 1)) << 17) | (unsigned)c;
            p[i] = atomicAdd(&lhist[b[i]], 1);
        } else b[i] = -1;
    }
    __syncthreads();
    if (t < 64) {   // wave-0 scan, 4 bins per lane (256 bins)
        int a0 = lhist[4*t], a1 = lhist[4*t+1], a2 = lhist[4*t+2], a3 = lhist[4*t+3];
        int s = a0 + a1 + a2 + a3;
        int incl = s;
        #pragma unroll
        for (int m = 1; m < 64; m <<= 1) {
            int tmp = __shfl_up(incl, m);
            if (t >= m) incl += tmp;
        }
        int excl = incl - s;
        sc[4*t] = excl; sc[4*t+1] = excl + a0;
        sc[4*t+2] = excl + a0 + a1; sc[4*t+3] = excl + a0 + a1 + a2;
    }
    __syncthreads();
    int total = sc[NBMAX - 1] + lhist[NBMAX - 1];   // = min(CHUNK, E-base)
    #pragma unroll
    for (int i = 0; i < 8; ++i)
        if (b[i] >= 0) sstage[sc[b[i]] + p[i]] = pk[i];
    if (t < 257) sc_g[blockIdx.x * 257 + t] = (t < 256) ? sc[t] : total;
    __syncthreads();
    for (int i = t; i < total; i += 512)
        ebuf[base + i] = sstage[i];          // contiguous, full lines
}

// One block per bucket: gather the bucket's 391 per-chunk segments into LDS
// (wave-cooperative, read-side only), then degree hist + scan -> dvals/rptr,
// counting-sort csr_col. ebase/cnt from sc_g sums — zero global atomics.
__global__ __launch_bounds__(1024) void k_group(const int* __restrict__ sc_g,
                                                const unsigned* __restrict__ ebuf,
                                                int N, int NBK, int NCH,
                                                float* __restrict__ dvals,
                                                int* __restrict__ rptr,
                                                int* __restrict__ csr_col,
                                                unsigned short* __restrict__ Hs) {
    __shared__ unsigned sebuf[SCAP];   // 40 KB
    __shared__ int lhist[BROWS];       // hist, then cursor
    __shared__ int chS[NCHMAX], chO[NCHMAX], chL[NCHMAX];
    __shared__ int wtot[16], woff[16];
    __shared__ int sEbase, sCnt;
    int bkt = blockIdx.x, t = threadIdx.x;
    int lane = t & 63, wv = t >> 6;

    int s0 = 0, len = 0;
    if (t < NCH) {
        s0 = sc_g[t * 257 + bkt];
        len = sc_g[t * 257 + bkt + 1] - s0;   // adjacent -> same cache line
    }
    if (t == 0) sEbase = 0;
    if (t < BROWS) lhist[t] = 0;
    __syncthreads();
    if (t < NCH) { chS[t] = s0; atomicAdd(&sEbase, s0); }
    int incl = len;                           // scan chunk lens (16 waves)
    #pragma unroll
    for (int m = 1; m < 64; m <<= 1) {
        int tmp = __shfl_up(incl, m);
        if (lane >= m) incl += tmp;
    }
    if (lane == 63) wtot[wv] = incl;
    __syncthreads();
    if (t < 16) {
        int w = wtot[t];
        int wincl = w;
        #pragma unroll
        for (int m = 1; m < 16; m <<= 1) {
            int tmp = __shfl_up(wincl, m);
            if (t >= m) wincl += tmp;
        }
        woff[t] = wincl - w;
        if (t == 15) sCnt = wincl;
    }
    __syncthreads();
    if (t < NCH) {
        int off = woff[wv] + incl - len;
        int l = len;
        if (off > SCAP) off = SCAP;           // 22-sigma safety clamp
        if (off + l > SCAP) l = SCAP - off;
        chO[t] = off;
        chL[t] = l;
    }
    __syncthreads();
    // wave-cooperative segment copy: wave wv handles chunks wv, wv+16, ...
    for (int ch = wv; ch < NCH; ch += 16) {
        int so = chS[ch], off = chO[ch], l = chL[ch];
        for (int b0 = 0; b0 < l; b0 += 64) {
            int k = b0 + lane;
            if (k < l) sebuf[off + k] = ebuf[(size_t)ch * CHUNK + so + k];
        }
    }
    __syncthreads();
    int cnt = sCnt; if (cnt > SCAP) cnt = SCAP;
    for (int i = t; i < cnt; i += 1024)
        atomicAdd(&lhist[sebuf[i] >> 17], 1);
    __syncthreads();
    int v = 0, incl2 = 0;
    if (t < BROWS) {    // 8 waves scan 512 degrees
        v = lhist[t];
        incl2 = v;
        #pragma unroll
        for (int m = 1; m < 64; m <<= 1) {
            int tmp = __shfl_up(incl2, m);
            if (lane >= m) incl2 += tmp;
        }
        if (lane == 63) wtot[wv] = incl2;
    }
    __syncthreads();
    if (t < 8) {
        int w = wtot[t];
        int wincl = w;
        #pragma unroll
        for (int m = 1; m < 8; m <<= 1) {
            int tmp = __shfl_up(wincl, m);
            if (t >= m) wincl += tmp;
        }
        woff[t] = wincl - w;
    }
    __syncthreads();
    int ebase = sEbase;
    if (t < BROWS) {
        int excl = woff[wv] + incl2 - v;
        int r = (bkt << LOGB) + t;
        if (r < N) {
            rptr[r] = ebase + excl;
            dvals[r] = rsqrtf((float)v);
        }
        lhist[t] = excl;              // becomes running cursor
    }
    if (bkt == NBK - 1 && t == 0) rptr[N] = ebase + cnt;
    if (bkt == 0 && t == 0) dvals[N] = 0.f;   // pad slot
    if (bkt == 0 && t < 64)                    // zero row N of Hs (gather pad)
        ((unsigned*)(Hs + (size_t)N * D))[t] = 0u;
    __syncthreads();
    for (int i = t; i < cnt; i += 1024) {
        unsigned e = sebuf[i];
        int rr = (int)(e >> 17);
        int p = atomicAdd(&lhist[rr], 1);
        csr_col[ebase + p] = (int)(e & 0x1FFFFu);
    }
}

// GEMM-FIRST: Hs[r][:] = bf16(d_r * (x[r] @ W^T + b)).
__global__ __launch_bounds__(256, 2) void k_gc(const float* __restrict__ x,
                                               const unsigned short* __restrict__ Wbh,
                                               const unsigned short* __restrict__ Wbl,
                                               const float* __restrict__ b,
                                               const float* __restrict__ dvals,
                                               unsigned short* __restrict__ Hs, int N) {
    __shared__ unsigned short Whi[128 * LDSW];   // 34.8 KB (reused as stage)
    __shared__ unsigned short Wlo[128 * LDSW];
    __shared__ float bs[D];
    int t = threadIdx.x;
    #pragma unroll
    for (int i = 0; i < 16; ++i) {
        int idx4 = i * 256 + t;          // ushort4 index, 4096 total
        int r = idx4 >> 5;
        int c = (idx4 & 31) * 4;
        ((ushort4*)&Whi[r * LDSW + c])[0] = ((const ushort4*)Wbh)[idx4];
        ((ushort4*)&Wlo[r * LDSW + c])[0] = ((const ushort4*)Wbl)[idx4];
    }
    if (t < D) bs[t] = b[t];
    __syncthreads();

    int wave = t >> 6, lane = t & 63;
    int quad = lane >> 4, mrow = lane & 15;
    int row_base = blockIdx.x * 128 + wave * 32;

    bf16x8 Ahi[2][4], Alo[2][4];
    #pragma unroll
    for (int s = 0; s < 2; ++s) {
        int grow = row_base + s * 16 + mrow;
        bool ok = grow < N;
        const float* xrow = x + (size_t)(ok ? grow : 0) * D;
        #pragma unroll
        for (int kk = 0; kk < 4; ++kk) {
            int k0 = kk * 32 + quad * 8;
            float4 f0 = ok ? ((const float4*)(xrow + k0))[0] : make_float4(0, 0, 0, 0);
            float4 f1 = ok ? ((const float4*)(xrow + k0))[1] : make_float4(0, 0, 0, 0);
            float fv[8] = {f0.x, f0.y, f0.z, f0.w, f1.x, f1.y, f1.z, f1.w};
            #pragma unroll
            for (int j = 0; j < 8; ++j) {
                unsigned short h = f2bf(fv[j]);
                Ahi[s][kk][j] = (short)h;
                Alo[s][kk][j] = (short)f2bf(fv[j] - bf2f(h));
            }
        }
    }

    f32x4 acc[2][8];
    #pragma unroll
    for (int s = 0; s < 2; ++s)
        #pragma unroll
        for (int ct = 0; ct < 8; ++ct)
            acc[s][ct] = (f32x4){0.f, 0.f, 0.f, 0.f};

    #pragma unroll
    for (int ct = 0; ct < 8; ++ct) {
        int wrow = ct * 16 + mrow;
        #pragma unroll
        for (int kk = 0; kk < 4; ++kk) {
            int off = wrow * LDSW + kk * 32 + quad * 8;
            bf16x8 Bhi = *(const bf16x8*)&Whi[off];
            bf16x8 Blo = *(const bf16x8*)&Wlo[off];
            #pragma unroll
            for (int s = 0; s < 2; ++s) {
                acc[s][ct] = __builtin_amdgcn_mfma_f32_16x16x32_bf16(Ahi[s][kk], Bhi, acc[s][ct], 0, 0, 0);
                acc[s][ct] = __builtin_amdgcn_mfma_f32_16x16x32_bf16(Alo[s][kk], Bhi, acc[s][ct], 0, 0, 0);
                acc[s][ct] = __builtin_amdgcn_mfma_f32_16x16x32_bf16(Ahi[s][kk], Blo, acc[s][ct], 0, 0, 0);
            }
        }
    }

    __syncthreads();                 // all waves done reading Whi/Wlo
    unsigned short* stage = Whi;     // alias: 128 x LDSW bf16 output tile
    #pragma unroll
    for (int s = 0; s < 2; ++s) {
        #pragma unroll
        for (int r = 0; r < 4; ++r) {
            int grow = row_base + s * 16 + quad * 4 + r;
            float dv = dvals[(grow < N) ? grow : N];   // dvals[N]=0
            int lrow = wave * 32 + s * 16 + quad * 4 + r;
            #pragma unroll
            for (int ct = 0; ct < 8; ++ct) {
                int col = ct * 16 + mrow;
                stage[lrow * LDSW + col] = f2bf(dv * (acc[s][ct][r] + bs[col]));
            }
        }
    }
    __syncthreads();
    for (int i = t; i < 128 * 16; i += 256) {   // 16B granules: 128 rows x 16
        int lrow = i >> 4;
        int g = i & 15;
        int grow = blockIdx.x * 128 + lrow;
        if (grow < N)
            ((uint4*)Hs)[(size_t)grow * 16 + g] =
                ((const uint4*)&stage[lrow * LDSW])[g];
    }
}

#define ACC8(v) do { \
    a[0] += bflo((v).x); a[1] += bfhi((v).x); \
    a[2] += bflo((v).y); a[3] += bfhi((v).y); \
    a[4] += bflo((v).z); a[5] += bfhi((v).z); \
    a[6] += bflo((v).w); a[7] += bfhi((v).w); } while (0)

// Wave per row over Hs, final-output kernel (measured stable 84-86 us).
__global__ __launch_bounds__(256) void k_rows(const unsigned short* __restrict__ Hs,
                                              const int* __restrict__ rptr,
                                              const int* __restrict__ csr_col,
                                              const float* __restrict__ dvals,
                                              float* __restrict__ out, int N) {
    int wid = (blockIdx.x * blockDim.x + threadIdx.x) >> 6;
    if (wid >= N) return;
    int lane = threadIdx.x & 63;
    int grp = lane >> 4, sl = lane & 15;
    int s = rptr[wid];
    int n = rptr[wid + 1] - s;
    const uint4* hv = (const uint4*)Hs;   // 16B granules, 16 per row

    int cc = csr_col[s + lane];           // unconditional (csr_col padded +64)
    int ccreg = (lane < n) ? cc : N;      // pad lanes -> zero row
    uint4 vself = hv[(size_t)wid * 16 + sl];

    float a[8] = {0.f, 0.f, 0.f, 0.f, 0.f, 0.f, 0.f, 0.f};
    int nf = (n < 64) ? n : 64;           // n >= 1 always (self edge in rows)

    // prologue: chunk 0 (pad lanes read the zero row -> contribute 0.0)
    int c0 = __shfl(ccreg, grp);
    int c1 = __shfl(ccreg, grp + 4);
    int c2 = __shfl(ccreg, grp + 8);
    int c3 = __shfl(ccreg, grp + 12);
    uint4 p0 = hv[(size_t)c0 * 16 + sl];
    uint4 p1 = hv[(size_t)c1 * 16 + sl];
    uint4 p2 = hv[(size_t)c2 * 16 + sl];
    uint4 p3 = hv[(size_t)c3 * 16 + sl];

    for (int k0 = 16; k0 < nf; k0 += 16) {
        int i0 = k0 + grp;                // shuffle idx < 64 always
        int d0 = __shfl(ccreg, i0);
        int d1 = __shfl(ccreg, i0 + 4);
        int d2 = __shfl(ccreg, i0 + 8);
        int d3 = __shfl(ccreg, i0 + 12);
        uint4 q0 = hv[(size_t)d0 * 16 + sl];
        uint4 q1 = hv[(size_t)d1 * 16 + sl];
        uint4 q2 = hv[(size_t)d2 * 16 + sl];
        uint4 q3 = hv[(size_t)d3 * 16 + sl];
        ACC8(p0); ACC8(p1); ACC8(p2); ACC8(p3);
        p0 = q0; p1 = q1; p2 = q2; p3 = q3;
    }
    ACC8(p0); ACC8(p1); ACC8(p2); ACC8(p3);     // epilogue: last chunk

    if (__builtin_expect(n > 64, 0)) {    // pathological high-degree fallback
        for (int idx = 64 + grp; idx < n; idx += 4) {
            int c = csr_col[s + idx];
            uint4 v = hv[(size_t)c * 16 + sl];
            ACC8(v);
        }
    }
    if (grp == 0) ACC8(vself);            // self-loop term

    #pragma unroll
    for (int j = 0; j < 8; ++j) {
        a[j] += __shfl_xor(a[j], 16);
        a[j] += __shfl_xor(a[j], 32);
    }
    float dr = dvals[wid];
    if (grp < 2) {
        float4 o = (grp == 0) ? make_float4(a[0], a[1], a[2], a[3])
                              : make_float4(a[4], a[5], a[6], a[7]);
        o.x *= dr; o.y *= dr; o.z *= dr; o.w *= dr;
        ((float4*)(out + (size_t)wid * D))[sl * 2 + grp] = o;
    }
}

extern "C" void kernel_launch(void* const* d_in, const int* in_sizes, int n_in,
                              void* d_out, int out_size, void* d_ws, size_t ws_size,
                              hipStream_t stream) {
    const float* x  = (const float*)d_in[0];
    const int*   ei = (const int*)d_in[1];
    const float* W  = (const float*)d_in[2];
    const float* b  = (const float*)d_in[3];
    float* out = (float*)d_out;
    int N = in_sizes[0] / D;
    int E = in_sizes[1] / 2;
    int NB = (N + BROWS - 1) / BROWS;        // 196
    int NCH = (E + CHUNK - 1) / CHUNK;       // 391

    int*            rptr    = (int*)d_ws;                // N+1
    float*          dvals   = (float*)(rptr + N + 1);    // N+1 (dvals[N]=0 pad)
    int*            csr_col = (int*)(dvals + N + 1);     // E+64 (uncond read pad)
    unsigned*       ebuf    = (unsigned*)(csr_col + E + 64);  // NCH*CHUNK
    int*            sc_g    = (int*)(ebuf + (size_t)NCH * CHUNK); // NCH*257
    unsigned short* Wbh     = (unsigned short*)(sc_g + (size_t)NCH * 257); // 16384
    unsigned short* Wbl     = Wbh + D * D;                                  // 16384
    uintptr_t hs_addr = (uintptr_t)(Wbl + D * D);
    hs_addr = (hs_addr + 15) & ~(uintptr_t)15;
    unsigned short* Hs = (unsigned short*)hs_addr;  // (N+1)*D bf16; row N zeros

    k_bin<<<NCH, 512, 0, stream>>>(ei, ei + E, E, ebuf, sc_g, W, Wbh, Wbl);
    k_group<<<NB, 1024, 0, stream>>>(sc_g, ebuf, N, NB, NCH, dvals, rptr, csr_col, Hs);
    k_gc<<<(N + 127) / 128, 256, 0, stream>>>(x, Wbh, Wbl, b, dvals, Hs, N);
    k_rows<<<(N + 3) / 4, 256, 0, stream>>>(Hs, rptr, csr_col, dvals, out, N);
}

// Round 13
// 230.327 us; speedup vs baseline: 1.0957x; 1.0280x over previous
//
#include <hip/hip_runtime.h>

#define D 128
#define BROWS 512       // rows per coarse bucket
#define LOGB 9
#define NBMAX 256       // max bins (N <= 131072)
#define CHUNK 4096      // edges per k_bin chunk
#define SCAP 10240      // LDS staging capacity per bucket (mean 8192, +22 sigma)
#define NCHMAX 512      // max chunks (E <= 2M)
#define LDSW 136        // padded LDS stride (shorts) for W planes / stage

typedef __attribute__((ext_vector_type(8))) short bf16x8;
typedef __attribute__((ext_vector_type(4))) float f32x4;

__device__ inline unsigned short f2bf(float f) {
    unsigned u = __float_as_uint(f);
    u += 0x7FFFu + ((u >> 16) & 1u);
    return (unsigned short)(u >> 16);
}
__device__ inline float bf2f(unsigned short h) {
    return __uint_as_float((unsigned)h << 16);
}
__device__ inline float bflo(unsigned u) { return __uint_as_float(u << 16); }
__device__ inline float bfhi(unsigned u) { return __uint_as_float(u & 0xFFFF0000u); }

// Bin edges into 256 bins; packed entry = (local_row<<17)|col. Entries are
// bin-sorted within the chunk but stored contiguously at ebuf[chunk*CHUNK]
// (full-line coalesced flush). Per-chunk bin prefix table sc_g[chunk][0..256].
// Blocks 0-7 additionally pre-convert W to bf16 hi/lo.
__global__ __launch_bounds__(512) void k_bin(const int* __restrict__ row,
                                             const int* __restrict__ col,
                                             int E, unsigned* __restrict__ ebuf,
                                             int* __restrict__ sc_g,
                                             const float* __restrict__ W,
                                             unsigned short* __restrict__ Wbh,
                                             unsigned short* __restrict__ Wbl) {
    __shared__ int lhist[NBMAX];
    __shared__ int sc[NBMAX];
    __shared__ unsigned sstage[CHUNK];
    int t = threadIdx.x;
    if (blockIdx.x < 8) {   // W -> bf16 hi/lo, 2048 elements per block
        int wb = blockIdx.x * 2048 + t;
        #pragma unroll
        for (int i = 0; i < 4; ++i) {
            int idx = wb + i * 512;
            float wv = W[idx];
            unsigned short h = f2bf(wv);
            Wbh[idx] = h;
            Wbl[idx] = f2bf(wv - bf2f(h));
        }
    }
    int base = blockIdx.x * CHUNK;
    if (t < NBMAX) lhist[t] = 0;
    __syncthreads();
    int b[8], p[8]; unsigned pk[8];
    #pragma unroll
    for (int i = 0; i < 8; ++i) {
        int idx = base + i * 512 + t;
        if (idx < E) {
            int r = row[idx], c = col[idx];
            b[i] = r >> LOGB;
            pk[i] = ((unsigned)(r & (BROWS - 1)) << 17) | (unsigned)c;
            p[i] = atomicAdd(&lhist[b[i]], 1);
        } else b[i] = -1;
    }
    __syncthreads();
    if (t < 64) {   // wave-0 scan, 4 bins per lane (256 bins)
        int a0 = lhist[4*t], a1 = lhist[4*t+1], a2 = lhist[4*t+2], a3 = lhist[4*t+3];
        int s = a0 + a1 + a2 + a3;
        int incl = s;
        #pragma unroll
        for (int m = 1; m < 64; m <<= 1) {
            int tmp = __shfl_up(incl, m);
            if (t >= m) incl += tmp;
        }
        int excl = incl - s;
        sc[4*t] = excl; sc[4*t+1] = excl + a0;
        sc[4*t+2] = excl + a0 + a1; sc[4*t+3] = excl + a0 + a1 + a2;
    }
    __syncthreads();
    int total = sc[NBMAX - 1] + lhist[NBMAX - 1];   // = min(CHUNK, E-base)
    #pragma unroll
    for (int i = 0; i < 8; ++i)
        if (b[i] >= 0) sstage[sc[b[i]] + p[i]] = pk[i];
    if (t < 257) sc_g[blockIdx.x * 257 + t] = (t < 256) ? sc[t] : total;
    __syncthreads();
    for (int i = t; i < total; i += 512)
        ebuf[base + i] = sstage[i];          // contiguous, full lines
}

// MERGED sort + GEMM: one 1024-thread block per bucket.
// Phase 1: gather the bucket's per-chunk segments into LDS, degree hist +
//   scan -> dvals/rptr/sdl, counting-sort csr_col (R11-proven).
// Phase 2: W bf16 planes staged into the (dead) sebuf region; the bucket's
//   512 rows GEMM'd in 2 passes of 16 rows/wave (acc[8]+A[8] ~ 90 VGPR --
//   fits the 128-VGPR cap at 16 waves/CU; R4 lesson: never let the gather/
//   GEMM state exceed the occupancy-implied cap). Pass output staged in the
//   upper 69.6 KB (disjoint from W planes) -> coalesced 16B Hs writes.
// Saves one dispatch (~13 us of launch gap) + the dvals round-trip.
__global__ __launch_bounds__(1024) void k_gs(const int* __restrict__ sc_g,
                                             const unsigned* __restrict__ ebuf,
                                             const float* __restrict__ x,
                                             const unsigned short* __restrict__ Wbh,
                                             const unsigned short* __restrict__ Wbl,
                                             const float* __restrict__ bias,
                                             int N, int NBK, int NCH,
                                             float* __restrict__ dvals,
                                             int* __restrict__ rptr,
                                             int* __restrict__ csr_col,
                                             unsigned short* __restrict__ Hs) {
    __shared__ __align__(16) unsigned char smem[139264];  // 136 KB union
    __shared__ int lhist[BROWS];
    __shared__ float sdl[BROWS];
    __shared__ int chS[NCHMAX], chO[NCHMAX], chL[NCHMAX];
    __shared__ int wtot[16], woff[16];
    __shared__ int sEbase, sCnt;
    __shared__ float bs[D];
    int bkt = blockIdx.x, t = threadIdx.x;
    int lane = t & 63, wv = t >> 6;
    unsigned* sebuf = (unsigned*)smem;

    // ---- phase 0: per-chunk segment table ----
    int s0 = 0, len = 0;
    if (t < NCH) {
        s0 = sc_g[t * 257 + bkt];
        len = sc_g[t * 257 + bkt + 1] - s0;
    }
    if (t == 0) sEbase = 0;
    if (t < BROWS) lhist[t] = 0;
    __syncthreads();
    if (t < NCH) { chS[t] = s0; atomicAdd(&sEbase, s0); }
    int incl = len;
    #pragma unroll
    for (int m = 1; m < 64; m <<= 1) {
        int tmp = __shfl_up(incl, m);
        if (lane >= m) incl += tmp;
    }
    if (lane == 63) wtot[wv] = incl;
    __syncthreads();
    if (t < 16) {
        int w0 = wtot[t];
        int wincl = w0;
        #pragma unroll
        for (int m = 1; m < 16; m <<= 1) {
            int tmp = __shfl_up(wincl, m);
            if (t >= m) wincl += tmp;
        }
        woff[t] = wincl - w0;
        if (t == 15) sCnt = wincl;
    }
    __syncthreads();
    if (t < NCH) {
        int off = woff[wv] + incl - len;
        int l = len;
        if (off > SCAP) off = SCAP;
        if (off + l > SCAP) l = SCAP - off;
        chO[t] = off;
        chL[t] = l;
    }
    __syncthreads();
    // ---- phase 1: segment copy, hist, scan, sort ----
    for (int ch = wv; ch < NCH; ch += 16) {
        int so = chS[ch], off = chO[ch], l = chL[ch];
        for (int b0 = 0; b0 < l; b0 += 64) {
            int k = b0 + lane;
            if (k < l) sebuf[off + k] = ebuf[(size_t)ch * CHUNK + so + k];
        }
    }
    __syncthreads();
    int cnt = sCnt; if (cnt > SCAP) cnt = SCAP;
    for (int i = t; i < cnt; i += 1024)
        atomicAdd(&lhist[sebuf[i] >> 17], 1);
    __syncthreads();
    int v = 0, incl2 = 0;
    if (t < BROWS) {
        v = lhist[t];
        incl2 = v;
        #pragma unroll
        for (int m = 1; m < 64; m <<= 1) {
            int tmp = __shfl_up(incl2, m);
            if (lane >= m) incl2 += tmp;
        }
        if (lane == 63) wtot[wv] = incl2;
    }
    __syncthreads();
    if (t < 8) {
        int w0 = wtot[t];
        int wincl = w0;
        #pragma unroll
        for (int m = 1; m < 8; m <<= 1) {
            int tmp = __shfl_up(wincl, m);
            if (t >= m) wincl += tmp;
        }
        woff[t] = wincl - w0;
    }
    __syncthreads();
    int ebase = sEbase;
    if (t < BROWS) {
        int excl = woff[wv] + incl2 - v;
        int r = (bkt << LOGB) + t;
        float dl = rsqrtf((float)v);     // v==0 -> inf, masked at use
        if (r < N) {
            rptr[r] = ebase + excl;
            dvals[r] = dl;
        }
        sdl[t] = dl;
        lhist[t] = excl;                 // becomes running cursor
    }
    if (bkt == NBK - 1 && t == 0) rptr[N] = ebase + cnt;
    if (bkt == 0 && t == 0) dvals[N] = 0.f;
    if (bkt == 0 && t < 64)              // zero row N of Hs (gather pad)
        ((unsigned*)(Hs + (size_t)N * D))[t] = 0u;
    __syncthreads();
    for (int i = t; i < cnt; i += 1024) {
        unsigned e = sebuf[i];
        int rr = (int)(e >> 17);
        int p = atomicAdd(&lhist[rr], 1);
        csr_col[ebase + p] = (int)(e & 0x1FFFFu);
    }
    __syncthreads();                     // sebuf dead; reuse smem for W

    // ---- phase 2: W planes + bias into LDS ----
    unsigned short* Whi = (unsigned short*)smem;              // 34816 B
    unsigned short* Wlo = (unsigned short*)(smem + 34816);    // 34816 B
    unsigned short* stage = (unsigned short*)(smem + 69632);  // 69632 B (256 rows)
    #pragma unroll
    for (int i = 0; i < 4; ++i) {
        int idx4 = i * 1024 + t;         // ushort4 index, 4096 total
        int r = idx4 >> 5;
        int c = (idx4 & 31) * 4;
        ((ushort4*)&Whi[r * LDSW + c])[0] = ((const ushort4*)Wbh)[idx4];
        ((ushort4*)&Wlo[r * LDSW + c])[0] = ((const ushort4*)Wbl)[idx4];
    }
    if (t < D) bs[t] = bias[t];
    __syncthreads();

    // ---- phase 3: GEMM, 2 passes x (16 waves x 16 rows) ----
    int w = wv, quad = lane >> 4, mrow = lane & 15;
    for (int p = 0; p < 2; ++p) {
        int rowbase = (bkt << LOGB) + p * 256 + w * 16;
        int grow = rowbase + mrow;
        bool ok = grow < N;
        const float* xrow = x + (size_t)(ok ? grow : 0) * D;
        bf16x8 Ahi[4], Alo[4];
        #pragma unroll
        for (int kk = 0; kk < 4; ++kk) {
            int k0 = kk * 32 + quad * 8;
            float4 f0 = ok ? ((const float4*)(xrow + k0))[0] : make_float4(0, 0, 0, 0);
            float4 f1 = ok ? ((const float4*)(xrow + k0))[1] : make_float4(0, 0, 0, 0);
            float fv[8] = {f0.x, f0.y, f0.z, f0.w, f1.x, f1.y, f1.z, f1.w};
            #pragma unroll
            for (int j = 0; j < 8; ++j) {
                unsigned short h = f2bf(fv[j]);
                Ahi[kk][j] = (short)h;
                Alo[kk][j] = (short)f2bf(fv[j] - bf2f(h));
            }
        }
        f32x4 acc[8];
        #pragma unroll
        for (int ct = 0; ct < 8; ++ct) acc[ct] = (f32x4){0.f, 0.f, 0.f, 0.f};
        #pragma unroll
        for (int ct = 0; ct < 8; ++ct) {
            int wrow = ct * 16 + mrow;
            #pragma unroll
            for (int kk = 0; kk < 4; ++kk) {
                int off = wrow * LDSW + kk * 32 + quad * 8;
                bf16x8 Bhi = *(const bf16x8*)&Whi[off];
                bf16x8 Blo = *(const bf16x8*)&Wlo[off];
                acc[ct] = __builtin_amdgcn_mfma_f32_16x16x32_bf16(Ahi[kk], Bhi, acc[ct], 0, 0, 0);
                acc[ct] = __builtin_amdgcn_mfma_f32_16x16x32_bf16(Alo[kk], Bhi, acc[ct], 0, 0, 0);
                acc[ct] = __builtin_amdgcn_mfma_f32_16x16x32_bf16(Ahi[kk], Blo, acc[ct], 0, 0, 0);
            }
        }
        // stage this pass's 256 rows (disjoint from live W planes)
        #pragma unroll
        for (int r2 = 0; r2 < 4; ++r2) {
            int lrow = w * 16 + quad * 4 + r2;        // [0,256)
            int gr = (bkt << LOGB) + p * 256 + lrow;
            float dv = (gr < N) ? sdl[p * 256 + lrow] : 0.f;
            #pragma unroll
            for (int ct = 0; ct < 8; ++ct) {
                int col = ct * 16 + mrow;
                stage[lrow * LDSW + col] = f2bf(dv * (acc[ct][r2] + bs[col]));
            }
        }
        __syncthreads();
        for (int i = t; i < 256 * 16; i += 1024) {    // 16B granules
            int lrow = i >> 4, g = i & 15;
            int gr = (bkt << LOGB) + p * 256 + lrow;
            if (gr < N)
                ((uint4*)Hs)[(size_t)gr * 16 + g] =
                    ((const uint4*)&stage[lrow * LDSW])[g];
        }
        __syncthreads();
    }
}

#define ACC8(v) do { \
    a[0] += bflo((v).x); a[1] += bfhi((v).x); \
    a[2] += bflo((v).y); a[3] += bfhi((v).y); \
    a[4] += bflo((v).z); a[5] += bfhi((v).z); \
    a[6] += bflo((v).w); a[7] += bfhi((v).w); } while (0)

// Wave per row over Hs, final-output kernel (measured stable 84-86 us).
__global__ __launch_bounds__(256) void k_rows(const unsigned short* __restrict__ Hs,
                                              const int* __restrict__ rptr,
                                              const int* __restrict__ csr_col,
                                              const float* __restrict__ dvals,
                                              float* __restrict__ out, int N) {
    int wid = (blockIdx.x * blockDim.x + threadIdx.x) >> 6;
    if (wid >= N) return;
    int lane = threadIdx.x & 63;
    int grp = lane >> 4, sl = lane & 15;
    int s = rptr[wid];
    int n = rptr[wid + 1] - s;
    const uint4* hv = (const uint4*)Hs;   // 16B granules, 16 per row

    int cc = csr_col[s + lane];           // unconditional (csr_col padded +64)
    int ccreg = (lane < n) ? cc : N;      // pad lanes -> zero row
    uint4 vself = hv[(size_t)wid * 16 + sl];

    float a[8] = {0.f, 0.f, 0.f, 0.f, 0.f, 0.f, 0.f, 0.f};
    int nf = (n < 64) ? n : 64;           // n >= 1 always (self edge in rows)

    int c0 = __shfl(ccreg, grp);
    int c1 = __shfl(ccreg, grp + 4);
    int c2 = __shfl(ccreg, grp + 8);
    int c3 = __shfl(ccreg, grp + 12);
    uint4 p0 = hv[(size_t)c0 * 16 + sl];
    uint4 p1 = hv[(size_t)c1 * 16 + sl];
    uint4 p2 = hv[(size_t)c2 * 16 + sl];
    uint4 p3 = hv[(size_t)c3 * 16 + sl];

    for (int k0 = 16; k0 < nf; k0 += 16) {
        int i0 = k0 + grp;                // shuffle idx < 64 always
        int d0 = __shfl(ccreg, i0);
        int d1 = __shfl(ccreg, i0 + 4);
        int d2 = __shfl(ccreg, i0 + 8);
        int d3 = __shfl(ccreg, i0 + 12);
        uint4 q0 = hv[(size_t)d0 * 16 + sl];
        uint4 q1 = hv[(size_t)d1 * 16 + sl];
        uint4 q2 = hv[(size_t)d2 * 16 + sl];
        uint4 q3 = hv[(size_t)d3 * 16 + sl];
        ACC8(p0); ACC8(p1); ACC8(p2); ACC8(p3);
        p0 = q0; p1 = q1; p2 = q2; p3 = q3;
    }
    ACC8(p0); ACC8(p1); ACC8(p2); ACC8(p3);     // epilogue: last chunk

    if (__builtin_expect(n > 64, 0)) {    // pathological high-degree fallback
        for (int idx = 64 + grp; idx < n; idx += 4) {
            int c = csr_col[s + idx];
            uint4 vv = hv[(size_t)c * 16 + sl];
            ACC8(vv);
        }
    }
    if (grp == 0) ACC8(vself);            // self-loop term

    #pragma unroll
    for (int j = 0; j < 8; ++j) {
        a[j] += __shfl_xor(a[j], 16);
        a[j] += __shfl_xor(a[j], 32);
    }
    float dr = dvals[wid];
    if (grp < 2) {
        float4 o = (grp == 0) ? make_float4(a[0], a[1], a[2], a[3])
                              : make_float4(a[4], a[5], a[6], a[7]);
        o.x *= dr; o.y *= dr; o.z *= dr; o.w *= dr;
        ((float4*)(out + (size_t)wid * D))[sl * 2 + grp] = o;
    }
}

extern "C" void kernel_launch(void* const* d_in, const int* in_sizes, int n_in,
                              void* d_out, int out_size, void* d_ws, size_t ws_size,
                              hipStream_t stream) {
    const float* x  = (const float*)d_in[0];
    const int*   ei = (const int*)d_in[1];
    const float* W  = (const float*)d_in[2];
    const float* b  = (const float*)d_in[3];
    float* out = (float*)d_out;
    int N = in_sizes[0] / D;
    int E = in_sizes[1] / 2;
    int NB = (N + BROWS - 1) / BROWS;        // 196
    int NCH = (E + CHUNK - 1) / CHUNK;       // 391

    int*            rptr    = (int*)d_ws;                // N+1
    float*          dvals   = (float*)(rptr + N + 1);    // N+1 (dvals[N]=0 pad)
    int*            csr_col = (int*)(dvals + N + 1);     // E+64 (uncond read pad)
    unsigned*       ebuf    = (unsigned*)(csr_col + E + 64);  // NCH*CHUNK
    int*            sc_g    = (int*)(ebuf + (size_t)NCH * CHUNK); // NCH*257
    unsigned short* Wbh     = (unsigned short*)(sc_g + (size_t)NCH * 257); // 16384
    unsigned short* Wbl     = Wbh + D * D;                                  // 16384
    uintptr_t hs_addr = (uintptr_t)(Wbl + D * D);
    hs_addr = (hs_addr + 15) & ~(uintptr_t)15;
    unsigned short* Hs = (unsigned short*)hs_addr;  // (N+1)*D bf16; row N zeros

    k_bin<<<NCH, 512, 0, stream>>>(ei, ei + E, E, ebuf, sc_g, W, Wbh, Wbl);
    k_gs<<<NB, 1024, 0, stream>>>(sc_g, ebuf, x, Wbh, Wbl, b, N, NB, NCH,
                                  dvals, rptr, csr_col, Hs);
    k_rows<<<(N + 3) / 4, 256, 0, stream>>>(Hs, rptr, csr_col, dvals, out, N);
}